// Round 13
// baseline (148.509 us; speedup 1.0000x reference)
//
#include <hip/hip_runtime.h>
#include <math.h>

#define H 4096
#define W 4096
#define NC 512            // cells per dim (H/8)
#define NB 510            // blocks per dim (NC - 3 + 1)
#define ORI 9
#define NCELLS (NC * NC)  // 262144
#define NOUT (NB * NB * 81)  // 21068100

// ---- glibc flt-32 atanf/atan2f replication (fdlibm; pre-2.40 glibc) ----
__device__ __constant__ float c_atanhi[4] = {
    4.6364760399e-01f, 7.8539812565e-01f, 9.8279368877e-01f, 1.5707962513e+00f,
};
__device__ __constant__ float c_atanlo[4] = {
    5.0121582440e-09f, 3.7748947079e-08f, 3.4473217170e-08f, 7.5497894159e-08f,
};

__device__ float fdlibm_atanf(float x) {
#pragma clang fp contract(off)
    const float one = 1.0f;
    const float aT0  = (float) 3.33333333333329318027e-01;
    const float aT1  = (float)-1.99999999998764832476e-01;
    const float aT2  = (float) 1.42857142725034663711e-01;
    const float aT3  = (float)-1.11111104054623557880e-01;
    const float aT4  = (float) 9.09088713343650656196e-02;
    const float aT5  = (float)-7.69187620504482999495e-02;
    const float aT6  = (float) 6.66107313738753120669e-02;
    const float aT7  = (float)-5.83357013379057348645e-02;
    const float aT8  = (float) 4.97687799461593236017e-02;
    const float aT9  = (float)-3.65315727442169155270e-02;
    const float aT10 = (float) 1.62858201153657823623e-02;
    int hx = __float_as_int(x);
    int ix = hx & 0x7fffffff;
    int id;
    if (ix >= 0x4c800000) {
        if (ix > 0x7f800000) return x + x;
        float r = c_atanhi[3] + c_atanlo[3];
        return (hx > 0) ? r : -r;
    }
    if (ix < 0x3ee00000) {
        if (ix < 0x31000000) return x;
        id = -1;
    } else {
        x = fabsf(x);
        if (ix < 0x3f980000) {
            if (ix < 0x3f300000) { id = 0; x = (2.0f * x - one) / (2.0f + x); }
            else                 { id = 1; x = (x - one) / (x + one); }
        } else {
            if (ix < 0x401c0000) { id = 2; x = (x - 1.5f) / (one + 1.5f * x); }
            else                 { id = 3; x = -1.0f / x; }
        }
    }
    float z = x * x;
    float w = z * z;
    float s1 = z * (aT0 + w * (aT2 + w * (aT4 + w * (aT6 + w * (aT8 + w * aT10)))));
    float s2 = w * (aT1 + w * (aT3 + w * (aT5 + w * (aT7 + w * aT9))));
    if (id < 0) return x - x * (s1 + s2);
    z = c_atanhi[id] - ((x * (s1 + s2) - c_atanlo[id]) - x);
    return (hx < 0) ? -z : z;
}

__device__ float fdlibm_atan2f(float y, float x) {
#pragma clang fp contract(off)
    const float tiny   = 1.0e-30f;
    const float pi     = 3.1415927410e+00f;
    const float pi_lo  = -8.7422776573e-08f;
    const float pi_o_2 = 1.5707963705e+00f;
    int hx = __float_as_int(x), ix = hx & 0x7fffffff;
    int hy = __float_as_int(y), iy = hy & 0x7fffffff;
    if (ix > 0x7f800000 || iy > 0x7f800000) return x + y;
    if (hx == 0x3f800000) return fdlibm_atanf(y);
    int m = ((hy >> 31) & 1) | ((hx >> 30) & 2);
    if (iy == 0) {
        switch (m) {
            case 0: case 1: return y;
            case 2: return pi + tiny;
            default: return -pi - tiny;
        }
    }
    if (ix == 0) return (hy < 0) ? -pi_o_2 - tiny : pi_o_2 + tiny;
    if (ix == 0x7f800000) {
        if (iy == 0x7f800000) {
            switch (m) {
                case 0: return pi_o_2 * 0.5f + tiny;
                case 1: return -(pi_o_2 * 0.5f) - tiny;
                case 2: return 1.5f * pi_o_2 + tiny;
                default: return -(1.5f * pi_o_2) - tiny;
            }
        } else {
            switch (m) {
                case 0: return 0.0f;
                case 1: return -0.0f;
                case 2: return pi + tiny;
                default: return -pi - tiny;
            }
        }
    }
    if (iy == 0x7f800000) return (hy < 0) ? -pi_o_2 - tiny : pi_o_2 + tiny;
    int k = (iy - ix) >> 23;
    float z;
    if (k > 26) { z = pi_o_2 + 0.5f * pi_lo; m &= 1; }
    else if (k < -26 && hx < 0) z = 0.0f;
    else z = fdlibm_atanf(fabsf(y / x));
    switch (m) {
        case 0: return z;
        case 1: return -z;
        case 2: return pi - (z - pi_lo);
        default: return (z - pi_lo) - pi;
    }
}

// Exact-replica binning (slow path). Returns 0..8, or 9 == excluded (m==180 quirk).
__device__ __noinline__ int slow_bin(float gy, float gx) {
#pragma clang fp contract(off)
    float ang = fdlibm_atan2f(gy, gx);
    const float RAD2DEG = (float)(180.0 / 3.14159265358979323846264338328);
    float deg = ang * RAD2DEG;
    float m = fmodf(deg, 180.0f);
    if (m < 0.0f) m += 180.0f;
    int bin = (int)(m / 20.0f);
    if (bin < 9 && m >= (float)((bin + 1) * 20)) bin++;
    else if (bin > 0 && m < (float)(bin * 20)) bin--;
    return bin;
}

// Kernel A: wave-autonomous slabs — NO __syncthreads anywhere.
// Wave = one cell-row strip (8 rows x 64 cols = 8 cells). The wave stages its
// own 10x68 sqrt tile into a wave-private LDS region (producer == consumer),
// then computes gradients via 9x ds_read_b128, tangent-threshold binning,
// native ds_add_f32 histogram, and writes its 72 hist floats + 8 q values.
// Rationale: r6-r12 were frozen at ~110us / VALUBusy 23% by the block-wide
// barrier convoy (all resident blocks phase-locked: stage -> barrier -> VALU
// burst). Removing the barrier lets waves desync and overlap phases.
__global__ __launch_bounds__(256) void hog_hist(const float* __restrict__ x,
                                                float* __restrict__ hist,
                                                float* __restrict__ q) {
    __shared__ __align__(16) float S[4 * 680];  // 4 waves x 10 rows x 68 cols
    __shared__ float lh[4 * 72];                // per-wave 8 cells x 9 bins
    int t = threadIdx.x;
    int w = t >> 6, lane = t & 63;
    int wid = blockIdx.x * 4 + w;
    int crow = wid >> 6;            // cell row 0..511
    int strip = wid & 63;           // 64-col strip 0..63
    int col0 = strip << 6;
    int r0 = (crow << 3) - 1;       // top staged row (image coords)

    float* T = &S[w * 680];         // this wave's tile: T[k][c] = T[k*68+c]
    // wave-private histogram init (own wave only -> no barrier needed)
    lh[w * 72 + lane] = 0.0f;
    if (lane < 8) lh[w * 72 + 64 + lane] = 0.0f;

    // ---- stage: 10 coalesced row loads + halo columns, then sqrt -> LDS ----
    float v[10];
#pragma unroll
    for (int k = 0; k < 10; ++k) {
        int rk = r0 + k;
        v[k] = ((unsigned)rk < (unsigned)H) ? x[rk * W + col0 + lane] : 0.0f;
    }
    float vhalo = 0.0f;
    bool hl = (lane < 10);
    bool hr = (lane >= 10 && lane < 20);
    if (hl) {
        int rk = r0 + lane;
        if ((unsigned)rk < (unsigned)H && col0 >= 1) vhalo = x[rk * W + col0 - 1];
    } else if (hr) {
        int rk = r0 + lane - 10;
        if ((unsigned)rk < (unsigned)H && col0 + 64 < W) vhalo = x[rk * W + col0 + 64];
    }
    // image col col0+c at dword c+2; left halo at dword 1; right halo at 66.
#pragma unroll
    for (int k = 0; k < 10; ++k)
        T[k * 68 + lane + 2] = sqrtf(v[k]);          // IEEE-exact (np.sqrt)
    if (hl)      T[lane * 68 + 1]         = sqrtf(vhalo);
    else if (hr) T[(lane - 10) * 68 + 66] = sqrtf(vhalo);
    // (compiler inserts lgkmcnt before the dependent ds_reads below)

    // ---- compute: lane = (row-in-strip, cell) ----
    int cell = lane & 7;
    int rr8  = lane >> 3;            // 0..7 row within strip
    int grow = (crow << 3) + rr8;    // image row
    int gc0  = col0 + (cell << 3);
    bool row_ok = (grow >= 1) && (grow <= H - 2);

    const float4* Sv = (const float4*)S;
    int fa = w * 170 + rr8 * 17 + 2 * cell;   // float4 units; 16B-aligned
    float A[12], O[12], B[12];
    *(float4*)&A[0] = Sv[fa];      *(float4*)&A[4] = Sv[fa + 1];  *(float4*)&A[8] = Sv[fa + 2];
    *(float4*)&O[0] = Sv[fa + 17]; *(float4*)&O[4] = Sv[fa + 18]; *(float4*)&O[8] = Sv[fa + 19];
    *(float4*)&B[0] = Sv[fa + 34]; *(float4*)&B[4] = Sv[fa + 35]; *(float4*)&B[8] = Sv[fa + 36];

    const float T1 = (float) 0.36397023426620236135;  // tan20
    const float T2 = (float) 0.83909963117728001176;  // tan40
    const float T3 = (float) 1.73205080756887729353;  // tan60
    const float T4 = (float) 5.67128181961771110517;  // tan80
    float* lw = &lh[w * 72 + cell * 9];

#pragma unroll
    for (int i = 0; i < 8; ++i) {
        // pixel (grow, gc0+i): dword index i+2 in A/O/B
        float gy = row_ok ? (B[i + 2] - A[i + 2]) : 0.0f;
        unsigned gcu = (unsigned)(gc0 + i);
        float gx = (gcu - 1u < (unsigned)(W - 2)) ? (O[i + 3] - O[i + 1]) : 0.0f;

        float a = fabsf(gy), b = fabsf(gx);
        float d1 = fmaf(b, -T1, a);
        float d2 = fmaf(b, -T2, a);
        float d3 = fmaf(b, -T3, a);
        float d4 = fmaf(b, -T4, a);
        int cnt = (d1 > 0.0f) + (d2 > 0.0f) + (d3 > 0.0f) + (d4 > 0.0f);
        bool opp = ((__float_as_int(gy) ^ __float_as_int(gx)) < 0);
        int bin = opp ? 8 - cnt : cnt;

        // near-boundary / near-horizontal guard -> bit-exact fallback
        float cm = fminf(fminf(fabsf(d1), fabsf(d2)), fminf(fabsf(d3), fabsf(d4)));
        cm = fminf(cm, a);
        if (cm < 1e-5f * (a + b)) bin = slow_bin(gy, gx);

        float mag = __builtin_amdgcn_sqrtf(fmaf(gy, gy, gx * gx)); // value-level only
        if (bin < ORI) atomicAdd(&lw[bin], mag);   // native ds_add_f32 (r12-proven)
    }

    // ---- epilogue: wave-private lh -> hist + per-cell q ----
    int cbase = crow * (NC * ORI) + strip * 72;
    hist[cbase + lane] = lh[w * 72 + lane] * (1.0f / 64.0f);
    if (lane < 8) {
        hist[cbase + 64 + lane] = lh[w * 72 + 64 + lane] * (1.0f / 64.0f);
        float qq = 0.0f;
#pragma unroll
        for (int o = 0; o < 9; ++o) {
            float h = lh[w * 72 + lane * 9 + o] * (1.0f / 64.0f);
            qq = fmaf(h, h, qq);
        }
        q[crow * NC + strip * 8 + lane] = qq;
    }
}

// Kernel B: inv(i,j) = rsqrt(3x3 box-sum of q + EPS^2)
__global__ __launch_bounds__(256) void hog_inv(const float* __restrict__ q,
                                               float* __restrict__ inv) {
    int t = blockIdx.x * 256 + threadIdx.x;
    if (t >= NB * NB) return;
    int i = t / NB;
    int j = t - i * NB;
    float ssq = 0.0f;
#pragma unroll
    for (int bi = 0; bi < 3; ++bi)
#pragma unroll
        for (int bj = 0; bj < 3; ++bj)
            ssq += q[(i + bi) * NC + (j + bj)];
    inv[t] = 1.0f / sqrtf(ssq + 1e-10f);
}

// Kernel C: thread per output element, coalesced stores.
__global__ __launch_bounds__(256) void hog_norm(const float* __restrict__ hist,
                                                const float* __restrict__ inv,
                                                float* __restrict__ out, int n) {
    int k = blockIdx.x * 256 + threadIdx.x;
    if (k >= n) return;
    int pidx = k / 81;
    int e = k - pidx * 81;
    int i = pidx / NB;
    int j = pidx - i * NB;
    int bi = e / 27;
    int r = e - bi * 27;
    int bj = r / 9;
    int o = r - bj * 9;
    out[k] = hist[((i + bi) * NC + (j + bj)) * ORI + o] * inv[pidx];
}

extern "C" void kernel_launch(void* const* d_in, const int* in_sizes, int n_in,
                              void* d_out, int out_size, void* d_ws, size_t ws_size,
                              hipStream_t stream) {
    const float* x = (const float*)d_in[0];
    float* out = (float*)d_out;
    float* hist = (float*)d_ws;                     // 9.44 MB
    float* inv  = hist + NCELLS * ORI;              // 1.04 MB
    float* q = out + (NOUT - NCELLS);               // parked in d_out tail

    hog_hist<<<(NC * 64) / 4, 256, 0, stream>>>(x, hist, q);   // 8192 blocks
    hog_inv<<<(NB * NB + 255) / 256, 256, 0, stream>>>(q, inv);
    hog_norm<<<(out_size + 255) / 256, 256, 0, stream>>>(hist, inv, out, out_size);
}

// Round 14
// 145.216 us; speedup vs baseline: 1.0227x; 1.0227x over previous
//
#include <hip/hip_runtime.h>
#include <math.h>

#define H 4096
#define W 4096
#define NC 512            // cells per dim (H/8)
#define NB 510            // blocks per dim (NC - 3 + 1)
#define ORI 9
#define NCELLS (NC * NC)  // 262144
#define NOUT (NB * NB * 81)  // 21068100

// ---- glibc flt-32 atanf/atan2f replication (fdlibm; pre-2.40 glibc) ----
// FULLY INLINED: a __noinline__ call inside the pixel loop forced caller-saved
// spills around 8 call sites since r4 — the root cause of the VGPR=12..24 /
// VALUBusy~23% freeze (r5-r13). No calls may exist in the hot loop.
__device__ __forceinline__ float fdlibm_atanf(float x) {
#pragma clang fp contract(off)
    const float one = 1.0f;
    const float aT0  = (float) 3.33333333333329318027e-01;
    const float aT1  = (float)-1.99999999998764832476e-01;
    const float aT2  = (float) 1.42857142725034663711e-01;
    const float aT3  = (float)-1.11111104054623557880e-01;
    const float aT4  = (float) 9.09088713343650656196e-02;
    const float aT5  = (float)-7.69187620504482999495e-02;
    const float aT6  = (float) 6.66107313738753120669e-02;
    const float aT7  = (float)-5.83357013379057348645e-02;
    const float aT8  = (float) 4.97687799461593236017e-02;
    const float aT9  = (float)-3.65315727442169155270e-02;
    const float aT10 = (float) 1.62858201153657823623e-02;
    const float athi[4] = {4.6364760399e-01f, 7.8539812565e-01f,
                           9.8279368877e-01f, 1.5707962513e+00f};
    const float atlo[4] = {5.0121582440e-09f, 3.7748947079e-08f,
                           3.4473217170e-08f, 7.5497894159e-08f};
    int hx = __float_as_int(x);
    int ix = hx & 0x7fffffff;
    int id;
    if (ix >= 0x4c800000) {
        if (ix > 0x7f800000) return x + x;
        float r = athi[3] + atlo[3];
        return (hx > 0) ? r : -r;
    }
    if (ix < 0x3ee00000) {
        if (ix < 0x31000000) return x;
        id = -1;
    } else {
        x = fabsf(x);
        if (ix < 0x3f980000) {
            if (ix < 0x3f300000) { id = 0; x = (2.0f * x - one) / (2.0f + x); }
            else                 { id = 1; x = (x - one) / (x + one); }
        } else {
            if (ix < 0x401c0000) { id = 2; x = (x - 1.5f) / (one + 1.5f * x); }
            else                 { id = 3; x = -1.0f / x; }
        }
    }
    float z = x * x;
    float w = z * z;
    float s1 = z * (aT0 + w * (aT2 + w * (aT4 + w * (aT6 + w * (aT8 + w * aT10)))));
    float s2 = w * (aT1 + w * (aT3 + w * (aT5 + w * (aT7 + w * aT9))));
    if (id < 0) return x - x * (s1 + s2);
    z = athi[id] - ((x * (s1 + s2) - atlo[id]) - x);
    return (hx < 0) ? -z : z;
}

__device__ __forceinline__ float fdlibm_atan2f(float y, float x) {
#pragma clang fp contract(off)
    const float tiny   = 1.0e-30f;
    const float pi     = 3.1415927410e+00f;
    const float pi_lo  = -8.7422776573e-08f;
    const float pi_o_2 = 1.5707963705e+00f;
    int hx = __float_as_int(x), ix = hx & 0x7fffffff;
    int hy = __float_as_int(y), iy = hy & 0x7fffffff;
    if (hx == 0x3f800000) return fdlibm_atanf(y);
    int m = ((hy >> 31) & 1) | ((hx >> 30) & 2);
    if (iy == 0) {
        switch (m) {
            case 0: case 1: return y;
            case 2: return pi + tiny;
            default: return -pi - tiny;
        }
    }
    if (ix == 0) return (hy < 0) ? -pi_o_2 - tiny : pi_o_2 + tiny;
    int k = (iy - ix) >> 23;
    float z;
    if (k > 26) { z = pi_o_2 + 0.5f * pi_lo; m &= 1; }
    else if (k < -26 && hx < 0) z = 0.0f;
    else z = fdlibm_atanf(fabsf(y / x));
    switch (m) {
        case 0: return z;
        case 1: return -z;
        case 2: return pi - (z - pi_lo);
        default: return (z - pi_lo) - pi;
    }
}
// (inf/NaN clauses dropped: inputs are sqrt-differences of finite [0,1) data —
//  gy,gx are always finite; x==1.0 clause kept since gx can be 1.0 exactly? it
//  can't (max |gx|<1), but the clause is 1 cmp and keeps bit-exactness airtight.)

// Exact-replica binning (slow path) — INLINE. Returns 0..8, or 9 == excluded.
__device__ __forceinline__ int slow_bin(float gy, float gx) {
#pragma clang fp contract(off)
    float ang = fdlibm_atan2f(gy, gx);
    const float RAD2DEG = (float)(180.0 / 3.14159265358979323846264338328);
    float deg = ang * RAD2DEG;
    float m = fmodf(deg, 180.0f);
    if (m < 0.0f) m += 180.0f;
    int bin = (int)(m / 20.0f);
    if (bin < 9 && m >= (float)((bin + 1) * 20)) bin++;
    else if (bin > 0 && m < (float)(bin * 20)) bin--;
    return bin;
}

// constant-folding component selector (d is compile-time after full unroll)
__device__ __forceinline__ float el(const float4& v0, const float4& v1,
                                    const float4& v2, int d) {
    switch (d) {
        case 0:  return v0.x;  case 1:  return v0.y;
        case 2:  return v0.z;  case 3:  return v0.w;
        case 4:  return v1.x;  case 5:  return v1.y;
        case 6:  return v1.z;  case 7:  return v1.w;
        case 8:  return v2.x;  case 9:  return v2.y;
        case 10: return v2.z;  default: return v2.w;
    }
}

// Kernel A: wave-autonomous slabs (r13 structure), no barriers, no calls,
// no type-punned arrays. Wave = 8 rows x 64 cols = 8 cells.
__global__ __launch_bounds__(256, 4) void hog_hist(const float* __restrict__ x,
                                                   float* __restrict__ hist,
                                                   float* __restrict__ q) {
    __shared__ __align__(16) float S[4 * 680];  // 4 waves x 10 rows x 68 cols
    __shared__ float lh[4 * 72];                // per-wave 8 cells x 9 bins
    int t = threadIdx.x;
    int w = t >> 6, lane = t & 63;
    int wid = blockIdx.x * 4 + w;
    int crow = wid >> 6;            // cell row 0..511
    int strip = wid & 63;           // 64-col strip 0..63
    int col0 = strip << 6;
    int r0 = (crow << 3) - 1;       // top staged row (image coords)

    float* T = &S[w * 680];
    lh[w * 72 + lane] = 0.0f;
    if (lane < 8) lh[w * 72 + 64 + lane] = 0.0f;

    // ---- stage: 10 coalesced row loads + halo cols, sqrt -> LDS ----
    float v[10];
#pragma unroll
    for (int k = 0; k < 10; ++k) {
        int rk = r0 + k;
        v[k] = ((unsigned)rk < (unsigned)H) ? x[rk * W + col0 + lane] : 0.0f;
    }
    float vhalo = 0.0f;
    bool hl = (lane < 10);
    bool hr = (lane >= 10 && lane < 20);
    if (hl) {
        int rk = r0 + lane;
        if ((unsigned)rk < (unsigned)H && col0 >= 1) vhalo = x[rk * W + col0 - 1];
    } else if (hr) {
        int rk = r0 + lane - 10;
        if ((unsigned)rk < (unsigned)H && col0 + 64 < W) vhalo = x[rk * W + col0 + 64];
    }
#pragma unroll
    for (int k = 0; k < 10; ++k)
        T[k * 68 + lane + 2] = sqrtf(v[k]);          // IEEE-exact (np.sqrt)
    if (hl)      T[lane * 68 + 1]         = sqrtf(vhalo);
    else if (hr) T[(lane - 10) * 68 + 66] = sqrtf(vhalo);

    // ---- compute: lane = (row-in-strip, cell); 9x ds_read_b128 -> float4 regs ----
    int cell = lane & 7;
    int rr8  = lane >> 3;
    int grow = (crow << 3) + rr8;
    int gc0  = col0 + (cell << 3);
    bool row_ok = (grow >= 1) && (grow <= H - 2);

    const float4* Sv = (const float4*)S;
    int fa = w * 170 + rr8 * 17 + 2 * cell;
    float4 a0 = Sv[fa];      float4 a1 = Sv[fa + 1];  float4 a2 = Sv[fa + 2];
    float4 o0 = Sv[fa + 17]; float4 o1 = Sv[fa + 18]; float4 o2 = Sv[fa + 19];
    float4 b0 = Sv[fa + 34]; float4 b1 = Sv[fa + 35]; float4 b2 = Sv[fa + 36];

    const float T1 = (float) 0.36397023426620236135;  // tan20
    const float T2 = (float) 0.83909963117728001176;  // tan40
    const float T3 = (float) 1.73205080756887729353;  // tan60
    const float T4 = (float) 5.67128181961771110517;  // tan80
    float* lw = &lh[w * 72 + cell * 9];

#pragma unroll
    for (int i = 0; i < 8; ++i) {
        float gy = row_ok ? (el(b0, b1, b2, i + 2) - el(a0, a1, a2, i + 2)) : 0.0f;
        unsigned gcu = (unsigned)(gc0 + i);
        float gx = (gcu - 1u < (unsigned)(W - 2))
                     ? (el(o0, o1, o2, i + 3) - el(o0, o1, o2, i + 1)) : 0.0f;

        float a = fabsf(gy), b = fabsf(gx);
        float d1 = fmaf(b, -T1, a);
        float d2 = fmaf(b, -T2, a);
        float d3 = fmaf(b, -T3, a);
        float d4 = fmaf(b, -T4, a);
        int cnt = (d1 > 0.0f) + (d2 > 0.0f) + (d3 > 0.0f) + (d4 > 0.0f);
        bool opp = ((__float_as_int(gy) ^ __float_as_int(gx)) < 0);
        int bin = opp ? 8 - cnt : cnt;

        float cm = fminf(fminf(fabsf(d1), fabsf(d2)), fminf(fabsf(d3), fabsf(d4)));
        cm = fminf(cm, a);
        if (cm < 1e-5f * (a + b)) bin = slow_bin(gy, gx);   // inline, execz-skipped

        float mag = __builtin_amdgcn_sqrtf(fmaf(gy, gy, gx * gx)); // value-level only
        if (bin < ORI) atomicAdd(&lw[bin], mag);            // native ds_add_f32
    }

    // ---- epilogue: wave-private lh -> hist + per-cell q ----
    int cbase = crow * (NC * ORI) + strip * 72;
    hist[cbase + lane] = lh[w * 72 + lane] * (1.0f / 64.0f);
    if (lane < 8) {
        hist[cbase + 64 + lane] = lh[w * 72 + 64 + lane] * (1.0f / 64.0f);
        float qq = 0.0f;
#pragma unroll
        for (int o = 0; o < 9; ++o) {
            float h = lh[w * 72 + lane * 9 + o] * (1.0f / 64.0f);
            qq = fmaf(h, h, qq);
        }
        q[crow * NC + strip * 8 + lane] = qq;
    }
}

// Kernel B: inv(i,j) = rsqrt(3x3 box-sum of q + EPS^2)
__global__ __launch_bounds__(256) void hog_inv(const float* __restrict__ q,
                                               float* __restrict__ inv) {
    int t = blockIdx.x * 256 + threadIdx.x;
    if (t >= NB * NB) return;
    int i = t / NB;
    int j = t - i * NB;
    float ssq = 0.0f;
#pragma unroll
    for (int bi = 0; bi < 3; ++bi)
#pragma unroll
        for (int bj = 0; bj < 3; ++bj)
            ssq += q[(i + bi) * NC + (j + bj)];
    inv[t] = 1.0f / sqrtf(ssq + 1e-10f);
}

// Kernel C: thread per output element, coalesced stores.
__global__ __launch_bounds__(256) void hog_norm(const float* __restrict__ hist,
                                                const float* __restrict__ inv,
                                                float* __restrict__ out, int n) {
    int k = blockIdx.x * 256 + threadIdx.x;
    if (k >= n) return;
    int pidx = k / 81;
    int e = k - pidx * 81;
    int i = pidx / NB;
    int j = pidx - i * NB;
    int bi = e / 27;
    int r = e - bi * 27;
    int bj = r / 9;
    int o = r - bj * 9;
    out[k] = hist[((i + bi) * NC + (j + bj)) * ORI + o] * inv[pidx];
}

extern "C" void kernel_launch(void* const* d_in, const int* in_sizes, int n_in,
                              void* d_out, int out_size, void* d_ws, size_t ws_size,
                              hipStream_t stream) {
    const float* x = (const float*)d_in[0];
    float* out = (float*)d_out;
    float* hist = (float*)d_ws;                     // 9.44 MB
    float* inv  = hist + NCELLS * ORI;              // 1.04 MB
    float* q = out + (NOUT - NCELLS);               // parked in d_out tail

    hog_hist<<<(NC * 64) / 4, 256, 0, stream>>>(x, hist, q);   // 8192 blocks
    hog_inv<<<(NB * NB + 255) / 256, 256, 0, stream>>>(q, inv);
    hog_norm<<<(out_size + 255) / 256, 256, 0, stream>>>(hist, inv, out, out_size);
}

// Round 15
// 134.638 us; speedup vs baseline: 1.1030x; 1.0786x over previous
//
#include <hip/hip_runtime.h>
#include <math.h>

#define H 4096
#define W 4096
#define NC 512            // cells per dim (H/8)
#define NB 510            // blocks per dim (NC - 3 + 1)
#define ORI 9
#define NCELLS (NC * NC)  // 262144
#define NOUT (NB * NB * 81)  // 21068100

// ---- glibc flt-32 atanf/atan2f replication (fdlibm; pre-2.40 glibc) ----
// Slow path only; must stay bit-exact. Inline (r14 proved calls were harmless,
// but inline keeps the execz-skip cheap).
__device__ __forceinline__ float fdlibm_atanf(float x) {
#pragma clang fp contract(off)
    const float one = 1.0f;
    const float aT0  = (float) 3.33333333333329318027e-01;
    const float aT1  = (float)-1.99999999998764832476e-01;
    const float aT2  = (float) 1.42857142725034663711e-01;
    const float aT3  = (float)-1.11111104054623557880e-01;
    const float aT4  = (float) 9.09088713343650656196e-02;
    const float aT5  = (float)-7.69187620504482999495e-02;
    const float aT6  = (float) 6.66107313738753120669e-02;
    const float aT7  = (float)-5.83357013379057348645e-02;
    const float aT8  = (float) 4.97687799461593236017e-02;
    const float aT9  = (float)-3.65315727442169155270e-02;
    const float aT10 = (float) 1.62858201153657823623e-02;
    const float athi[4] = {4.6364760399e-01f, 7.8539812565e-01f,
                           9.8279368877e-01f, 1.5707962513e+00f};
    const float atlo[4] = {5.0121582440e-09f, 3.7748947079e-08f,
                           3.4473217170e-08f, 7.5497894159e-08f};
    int hx = __float_as_int(x);
    int ix = hx & 0x7fffffff;
    int id;
    if (ix >= 0x4c800000) {
        if (ix > 0x7f800000) return x + x;
        float r = athi[3] + atlo[3];
        return (hx > 0) ? r : -r;
    }
    if (ix < 0x3ee00000) {
        if (ix < 0x31000000) return x;
        id = -1;
    } else {
        x = fabsf(x);
        if (ix < 0x3f980000) {
            if (ix < 0x3f300000) { id = 0; x = (2.0f * x - one) / (2.0f + x); }
            else                 { id = 1; x = (x - one) / (x + one); }
        } else {
            if (ix < 0x401c0000) { id = 2; x = (x - 1.5f) / (one + 1.5f * x); }
            else                 { id = 3; x = -1.0f / x; }
        }
    }
    float z = x * x;
    float w = z * z;
    float s1 = z * (aT0 + w * (aT2 + w * (aT4 + w * (aT6 + w * (aT8 + w * aT10)))));
    float s2 = w * (aT1 + w * (aT3 + w * (aT5 + w * (aT7 + w * aT9))));
    if (id < 0) return x - x * (s1 + s2);
    z = athi[id] - ((x * (s1 + s2) - atlo[id]) - x);
    return (hx < 0) ? -z : z;
}

__device__ __forceinline__ float fdlibm_atan2f(float y, float x) {
#pragma clang fp contract(off)
    const float tiny   = 1.0e-30f;
    const float pi     = 3.1415927410e+00f;
    const float pi_lo  = -8.7422776573e-08f;
    const float pi_o_2 = 1.5707963705e+00f;
    int hx = __float_as_int(x), ix = hx & 0x7fffffff;
    int hy = __float_as_int(y), iy = hy & 0x7fffffff;
    if (hx == 0x3f800000) return fdlibm_atanf(y);
    int m = ((hy >> 31) & 1) | ((hx >> 30) & 2);
    if (iy == 0) {
        switch (m) {
            case 0: case 1: return y;
            case 2: return pi + tiny;
            default: return -pi - tiny;
        }
    }
    if (ix == 0) return (hy < 0) ? -pi_o_2 - tiny : pi_o_2 + tiny;
    int k = (iy - ix) >> 23;
    float z;
    if (k > 26) { z = pi_o_2 + 0.5f * pi_lo; m &= 1; }
    else if (k < -26 && hx < 0) z = 0.0f;
    else z = fdlibm_atanf(fabsf(y / x));
    switch (m) {
        case 0: return z;
        case 1: return -z;
        case 2: return pi - (z - pi_lo);
        default: return (z - pi_lo) - pi;
    }
}
// (inputs are finite f32 sqrt-differences; inf/NaN clauses not reachable)

// EXACT bin for pixel (grow, gc): reload the 4 neighbors, IEEE sqrtf, exact
// f32 gradient, fdlibm atan2f, numpy deg/mod pipeline. Returns 0..8 or 9.
__device__ __forceinline__ int slow_bin_px(const float* __restrict__ x,
                                           int grow, int gc,
                                           bool row_ok, bool col_ok) {
#pragma clang fp contract(off)
    float gy = 0.0f, gx = 0.0f;
    if (row_ok)
        gy = sqrtf(x[(grow + 1) * W + gc]) - sqrtf(x[(grow - 1) * W + gc]);
    if (col_ok)
        gx = sqrtf(x[grow * W + gc + 1]) - sqrtf(x[grow * W + gc - 1]);
    float ang = fdlibm_atan2f(gy, gx);
    const float RAD2DEG = (float)(180.0 / 3.14159265358979323846264338328);
    float deg = ang * RAD2DEG;
    float m = fmodf(deg, 180.0f);
    if (m < 0.0f) m += 180.0f;
    int bin = (int)(m / 20.0f);
    if (bin < 9 && m >= (float)((bin + 1) * 20)) bin++;
    else if (bin > 0 && m < (float)(bin * 20)) bin--;
    return bin;   // 9 == m==180 quirk -> excluded
}

// Kernel A: NO LDS tile, NO barrier, NO shuffles. Wave = 8x64 px strip;
// lane = one column (cell = lane>>3). Ten row loads upfront -> registers ->
// fast v_sqrt; gy in-register; gx from 2 per-lane neighbor loads (L1-hit).
// Approx fast path guarded by an exact fdlibm fallback (guard widened by an
// absolute term covering the 2-ulp v_sqrt gradient error).
__global__ __launch_bounds__(256) void hog_hist(const float* __restrict__ x,
                                                float* __restrict__ hist,
                                                float* __restrict__ q) {
    __shared__ float lh[4 * 72];    // per-wave 8 cells x 9 bins
    int t = threadIdx.x;
    int w = t >> 6, lane = t & 63;
    int wid = blockIdx.x * 4 + w;
    int crow = wid >> 6;            // cell row 0..511
    int strip = wid & 63;           // 64-col strip
    int col0 = strip << 6;
    int gc = col0 + lane;           // this lane's image column

    lh[w * 72 + lane] = 0.0f;
    if (lane < 8) lh[w * 72 + 64 + lane] = 0.0f;

    // upfront: 10 row loads at column gc (rows crow*8-1 .. crow*8+8)
    int r0 = (crow << 3) - 1;
    bool ok0 = (crow > 0), ok9 = (crow < NC - 1);
    float s0 = ok0 ? x[(r0 + 0) * W + gc] : 0.0f;
    float s1v = x[(r0 + 1) * W + gc];
    float s2v = x[(r0 + 2) * W + gc];
    float s3v = x[(r0 + 3) * W + gc];
    float s4v = x[(r0 + 4) * W + gc];
    float s5v = x[(r0 + 5) * W + gc];
    float s6v = x[(r0 + 6) * W + gc];
    float s7v = x[(r0 + 7) * W + gc];
    float s8v = x[(r0 + 8) * W + gc];
    float s9v = ok9 ? x[(r0 + 9) * W + gc] : 0.0f;
    float s[10];
    s[0] = __builtin_amdgcn_sqrtf(s0);
    s[1] = __builtin_amdgcn_sqrtf(s1v);
    s[2] = __builtin_amdgcn_sqrtf(s2v);
    s[3] = __builtin_amdgcn_sqrtf(s3v);
    s[4] = __builtin_amdgcn_sqrtf(s4v);
    s[5] = __builtin_amdgcn_sqrtf(s5v);
    s[6] = __builtin_amdgcn_sqrtf(s6v);
    s[7] = __builtin_amdgcn_sqrtf(s7v);
    s[8] = __builtin_amdgcn_sqrtf(s8v);
    s[9] = __builtin_amdgcn_sqrtf(s9v);

    bool col_ok = (gc >= 1) && (gc <= W - 2);
    const float T1 = (float) 0.36397023426620236135;  // tan20
    const float T2 = (float) 0.83909963117728001176;  // tan40
    const float T3 = (float) 1.73205080756887729353;  // tan60
    const float T4 = (float) 5.67128181961771110517;  // tan80
    float* lw = &lh[w * 72 + (lane >> 3) * 9];

#pragma unroll
    for (int j = 0; j < 8; ++j) {
        int grow = (crow << 3) + j;
        bool row_ok = (grow >= 1) && (grow <= H - 2);   // wave-uniform
        float gy = row_ok ? (s[j + 2] - s[j]) : 0.0f;
        float sl = 0.0f, sr = 0.0f;
        if (col_ok) {
            sl = __builtin_amdgcn_sqrtf(x[grow * W + gc - 1]);
            sr = __builtin_amdgcn_sqrtf(x[grow * W + gc + 1]);
        }
        float gx = sr - sl;

        float a = fabsf(gy), b = fabsf(gx);
        float d1 = fmaf(b, -T1, a);
        float d2 = fmaf(b, -T2, a);
        float d3 = fmaf(b, -T3, a);
        float d4 = fmaf(b, -T4, a);
        int cnt = (d1 > 0.0f) + (d2 > 0.0f) + (d3 > 0.0f) + (d4 > 0.0f);
        bool opp = ((__float_as_int(gy) ^ __float_as_int(gx)) < 0);
        int bin = opp ? 8 - cnt : cnt;

        // guard: relative term = reference-pipeline angular error margin;
        // absolute term 4e-6 covers the <=8e-7 v_sqrt-induced d_k error.
        float cm = fminf(fminf(fabsf(d1), fabsf(d2)),
                         fminf(fminf(fabsf(d3), fabsf(d4)), a));
        if (cm < fmaf(1e-5f, a + b, 4e-6f))
            bin = slow_bin_px(x, grow, gc, row_ok, col_ok);

        float mag = __builtin_amdgcn_sqrtf(fmaf(gy, gy, gx * gx)); // value-level
        if (bin < ORI) atomicAdd(&lw[bin], mag);    // native ds_add_f32
    }

    // epilogue: wave-private lh -> hist + per-cell q (no barrier needed)
    int cbase = crow * (NC * ORI) + strip * 72;
    hist[cbase + lane] = lh[w * 72 + lane] * (1.0f / 64.0f);
    if (lane < 8) {
        hist[cbase + 64 + lane] = lh[w * 72 + 64 + lane] * (1.0f / 64.0f);
        float qq = 0.0f;
#pragma unroll
        for (int o = 0; o < 9; ++o) {
            float h = lh[w * 72 + lane * 9 + o] * (1.0f / 64.0f);
            qq = fmaf(h, h, qq);
        }
        q[crow * NC + strip * 8 + lane] = qq;
    }
}

// Kernel B: inv(i,j) = rsqrt(3x3 box-sum of q + EPS^2)
__global__ __launch_bounds__(256) void hog_inv(const float* __restrict__ q,
                                               float* __restrict__ inv) {
    int t = blockIdx.x * 256 + threadIdx.x;
    if (t >= NB * NB) return;
    int i = t / NB;
    int j = t - i * NB;
    float ssq = 0.0f;
#pragma unroll
    for (int bi = 0; bi < 3; ++bi)
#pragma unroll
        for (int bj = 0; bj < 3; ++bj)
            ssq += q[(i + bi) * NC + (j + bj)];
    inv[t] = 1.0f / sqrtf(ssq + 1e-10f);
}

// Kernel C: thread per output element, coalesced stores.
__global__ __launch_bounds__(256) void hog_norm(const float* __restrict__ hist,
                                                const float* __restrict__ inv,
                                                float* __restrict__ out, int n) {
    int k = blockIdx.x * 256 + threadIdx.x;
    if (k >= n) return;
    int pidx = k / 81;
    int e = k - pidx * 81;
    int i = pidx / NB;
    int j = pidx - i * NB;
    int bi = e / 27;
    int r = e - bi * 27;
    int bj = r / 9;
    int o = r - bj * 9;
    out[k] = hist[((i + bi) * NC + (j + bj)) * ORI + o] * inv[pidx];
}

extern "C" void kernel_launch(void* const* d_in, const int* in_sizes, int n_in,
                              void* d_out, int out_size, void* d_ws, size_t ws_size,
                              hipStream_t stream) {
    const float* x = (const float*)d_in[0];
    float* out = (float*)d_out;
    float* hist = (float*)d_ws;                     // 9.44 MB
    float* inv  = hist + NCELLS * ORI;              // 1.04 MB
    float* q = out + (NOUT - NCELLS);               // parked in d_out tail

    hog_hist<<<(NC * 64) / 4, 256, 0, stream>>>(x, hist, q);   // 8192 blocks
    hog_inv<<<(NB * NB + 255) / 256, 256, 0, stream>>>(q, inv);
    hog_norm<<<(out_size + 255) / 256, 256, 0, stream>>>(hist, inv, out, out_size);
}